// Round 1
// baseline (51.827 us; speedup 1.0000x reference)
//
#include <hip/hip_runtime.h>

// Fixed problem shape (from reference): B=4, T=4096, D=2048, K=4.
constexpr int Bsz = 4;
constexpr int T   = 4096;
constexpr int D   = 2048;
constexpr int Kt  = 4;

constexpr int D4      = D / 4;        // 512 float4 columns per row
constexpr int THREADS = 256;
constexpr int DBLK    = D4 / THREADS; // 2 d-blocks
constexpr int TT      = 16;           // t rows per thread (strip)
constexpr int TBLK    = T / TT;       // 256 t-strips

__device__ __forceinline__ float silu_f(float y) {
    return y / (1.0f + __expf(-y));
}

__device__ __forceinline__ float4 silu4(float4 y) {
    return make_float4(silu_f(y.x), silu_f(y.y), silu_f(y.z), silu_f(y.w));
}

__global__ __launch_bounds__(THREADS) void shortconv_silu_kernel(
    const float* __restrict__ x,     // [B, T, D]
    const float* __restrict__ w,     // [D, 1, K] -> flat [D][K]
    const float* __restrict__ bias,  // [D]
    float* __restrict__ out)         // [B, T, D]
{
    const int bid  = blockIdx.x;
    const int dblk = bid % DBLK;
    const int tblk = (bid / DBLK) % TBLK;
    const int b    = bid / (DBLK * TBLK);

    const int d4 = dblk * THREADS + threadIdx.x;  // this thread's float4 column
    const int t0 = tblk * TT;

    const float4* x4 = reinterpret_cast<const float4*>(x) + (size_t)b * T * D4 + d4;
    float4*       o4 = reinterpret_cast<float4*>(out)     + (size_t)b * T * D4 + d4;

    // Per-channel weights: w[d][k], k fastest -> float4 per channel.
    const float4* w4 = reinterpret_cast<const float4*>(w);
    const float4 wr0 = w4[d4 * 4 + 0];
    const float4 wr1 = w4[d4 * 4 + 1];
    const float4 wr2 = w4[d4 * 4 + 2];
    const float4 wr3 = w4[d4 * 4 + 3];
    const float4 bb  = reinterpret_cast<const float4*>(bias)[d4];

    // Transpose to tap-major: wk{k} = tap-k weights for the 4 channels.
    const float4 wk0 = make_float4(wr0.x, wr1.x, wr2.x, wr3.x);
    const float4 wk1 = make_float4(wr0.y, wr1.y, wr2.y, wr3.y);
    const float4 wk2 = make_float4(wr0.z, wr1.z, wr2.z, wr3.z);
    const float4 wk3 = make_float4(wr0.w, wr1.w, wr2.w, wr3.w);

    // Sliding window: xm3 = x[t-3], xm2 = x[t-2], xm1 = x[t-1].
    float4 xm3, xm2, xm1;
    if (t0 == 0) {
        xm3 = make_float4(0.f, 0.f, 0.f, 0.f);
        xm2 = xm3;
        xm1 = xm3;
    } else {
        xm3 = x4[(size_t)(t0 - 3) * D4];
        xm2 = x4[(size_t)(t0 - 2) * D4];
        xm1 = x4[(size_t)(t0 - 1) * D4];
    }

#pragma unroll
    for (int i = 0; i < TT; ++i) {
        const int t = t0 + i;
        const float4 x0 = x4[(size_t)t * D4];

        float4 y;
        y.x = fmaf(wk0.x, xm3.x, fmaf(wk1.x, xm2.x, fmaf(wk2.x, xm1.x, fmaf(wk3.x, x0.x, bb.x))));
        y.y = fmaf(wk0.y, xm3.y, fmaf(wk1.y, xm2.y, fmaf(wk2.y, xm1.y, fmaf(wk3.y, x0.y, bb.y))));
        y.z = fmaf(wk0.z, xm3.z, fmaf(wk1.z, xm2.z, fmaf(wk2.z, xm1.z, fmaf(wk3.z, x0.z, bb.z))));
        y.w = fmaf(wk0.w, xm3.w, fmaf(wk1.w, xm2.w, fmaf(wk2.w, xm1.w, fmaf(wk3.w, x0.w, bb.w))));

        o4[(size_t)t * D4] = silu4(y);

        xm3 = xm2;
        xm2 = xm1;
        xm1 = x0;
    }
}

extern "C" void kernel_launch(void* const* d_in, const int* in_sizes, int n_in,
                              void* d_out, int out_size, void* d_ws, size_t ws_size,
                              hipStream_t stream) {
    const float* x    = (const float*)d_in[0];
    const float* w    = (const float*)d_in[1];
    const float* bias = (const float*)d_in[2];
    float*       out  = (float*)d_out;

    const int grid = Bsz * TBLK * DBLK;  // 4 * 256 * 2 = 2048 blocks
    shortconv_silu_kernel<<<grid, THREADS, 0, stream>>>(x, w, bias, out);
}

// Round 2
// 48.171 us; speedup vs baseline: 1.0759x; 1.0759x over previous
//
#include <hip/hip_runtime.h>

// Fixed problem shape (from reference): B=4, T=4096, D=2048, K=4.
constexpr int Bsz = 4;
constexpr int T   = 4096;
constexpr int D   = 2048;

constexpr int D4      = D / 4;        // 512 float4 columns per row
constexpr int THREADS = 256;
constexpr int DBLK    = D4 / THREADS; // 2 d-blocks
constexpr int TT      = 16;           // t rows per thread (strip)
constexpr int TBLK    = T / TT;       // 256 t-strips

using f4 = __attribute__((ext_vector_type(4))) float;

__device__ __forceinline__ float silu_f(float y) {
    return y / (1.0f + __expf(-y));
}

__device__ __forceinline__ f4 silu4(f4 y) {
    f4 r;
    r.x = silu_f(y.x); r.y = silu_f(y.y); r.z = silu_f(y.z); r.w = silu_f(y.w);
    return r;
}

__global__ __launch_bounds__(THREADS) void shortconv_silu_kernel(
    const float* __restrict__ x,     // [B, T, D]
    const float* __restrict__ w,     // [D, 1, K] -> flat [D][K]
    const float* __restrict__ bias,  // [D]
    float* __restrict__ out)         // [B, T, D]
{
    const int bid  = blockIdx.x;
    const int dblk = bid % DBLK;
    const int tblk = (bid / DBLK) % TBLK;
    const int b    = bid / (DBLK * TBLK);

    const int d4 = dblk * THREADS + threadIdx.x;  // this thread's float4 column
    const int t0 = tblk * TT;

    const f4* x4 = reinterpret_cast<const f4*>(x) + (size_t)b * T * D4 + d4;
    f4*       o4 = reinterpret_cast<f4*>(out)     + (size_t)b * T * D4 + d4;

    // ---- Phase 1: issue ALL strip loads back-to-back (19 independent
    // global_load_dwordx4 in flight per wave -> high MLP). Static indexing
    // only (full unroll) so xr[] stays in registers.
    f4 xr[TT + 3];
    const int tm3 = t0 - 3;
    if (t0 == 0) {
        const f4 z = {0.f, 0.f, 0.f, 0.f};
        xr[0] = z; xr[1] = z; xr[2] = z;
#pragma unroll
        for (int i = 3; i < TT + 3; ++i)
            xr[i] = x4[(size_t)(tm3 + i) * D4];
    } else {
#pragma unroll
        for (int i = 0; i < TT + 3; ++i)
            xr[i] = x4[(size_t)(tm3 + i) * D4];
    }

    // Per-channel weights: w[d][k], k fastest -> one f4 per channel.
    const f4* w4 = reinterpret_cast<const f4*>(w);
    const f4 wr0 = w4[d4 * 4 + 0];
    const f4 wr1 = w4[d4 * 4 + 1];
    const f4 wr2 = w4[d4 * 4 + 2];
    const f4 wr3 = w4[d4 * 4 + 3];
    const f4 bb  = reinterpret_cast<const f4*>(bias)[d4];

    // Transpose to tap-major: wk{k} holds tap-k weights for the 4 channels.
    const f4 wk0 = {wr0.x, wr1.x, wr2.x, wr3.x};
    const f4 wk1 = {wr0.y, wr1.y, wr2.y, wr3.y};
    const f4 wk2 = {wr0.z, wr1.z, wr2.z, wr3.z};
    const f4 wk3 = {wr0.w, wr1.w, wr2.w, wr3.w};

    // ---- Phase 2: compute + non-temporal store (output is never re-read;
    // don't displace x from L2/L3).
#pragma unroll
    for (int i = 0; i < TT; ++i) {
        const f4 a = xr[i];       // x[t-3]
        const f4 c = xr[i + 1];   // x[t-2]
        const f4 d = xr[i + 2];   // x[t-1]
        const f4 e = xr[i + 3];   // x[t]

        f4 y;
        y.x = fmaf(wk0.x, a.x, fmaf(wk1.x, c.x, fmaf(wk2.x, d.x, fmaf(wk3.x, e.x, bb.x))));
        y.y = fmaf(wk0.y, a.y, fmaf(wk1.y, c.y, fmaf(wk2.y, d.y, fmaf(wk3.y, e.y, bb.y))));
        y.z = fmaf(wk0.z, a.z, fmaf(wk1.z, c.z, fmaf(wk2.z, d.z, fmaf(wk3.z, e.z, bb.z))));
        y.w = fmaf(wk0.w, a.w, fmaf(wk1.w, c.w, fmaf(wk2.w, d.w, fmaf(wk3.w, e.w, bb.w))));

        __builtin_nontemporal_store(silu4(y), &o4[(size_t)(t0 + i) * D4]);
    }
}

extern "C" void kernel_launch(void* const* d_in, const int* in_sizes, int n_in,
                              void* d_out, int out_size, void* d_ws, size_t ws_size,
                              hipStream_t stream) {
    const float* x    = (const float*)d_in[0];
    const float* w    = (const float*)d_in[1];
    const float* bias = (const float*)d_in[2];
    float*       out  = (float*)d_out;

    const int grid = Bsz * TBLK * DBLK;  // 4 * 256 * 2 = 2048 blocks
    shortconv_silu_kernel<<<grid, THREADS, 0, stream>>>(x, w, bias, out);
}

// Round 3
// 45.111 us; speedup vs baseline: 1.1489x; 1.0678x over previous
//
#include <hip/hip_runtime.h>

// Fixed problem shape (from reference): B=4, T=4096, D=2048, K=4.
constexpr int Bsz = 4;
constexpr int T   = 4096;
constexpr int D   = 2048;

constexpr int D4      = D / 4;        // 512 float4 columns per row
constexpr int THREADS = 256;
constexpr int DBLK    = D4 / THREADS; // 2 d-blocks
constexpr int TT      = 16;           // t rows per thread (strip)
constexpr int TBLK    = T / TT;       // 256 t-strips
constexpr int NXCD    = 8;

using f4 = __attribute__((ext_vector_type(4))) float;

__device__ __forceinline__ float silu_f(float y) {
    return y / (1.0f + __expf(-y));
}

__device__ __forceinline__ f4 silu4(f4 y) {
    f4 r;
    r.x = silu_f(y.x); r.y = silu_f(y.y); r.z = silu_f(y.z); r.w = silu_f(y.w);
    return r;
}

__global__ __launch_bounds__(THREADS) void shortconv_silu_kernel(
    const float* __restrict__ x,     // [B, T, D]
    const float* __restrict__ w,     // [D, 1, K] -> flat [D][K]
    const float* __restrict__ bias,  // [D]
    float* __restrict__ out)         // [B, T, D]
{
    // XCD-aware swizzle (T1): default dispatch round-robins blockIdx across
    // the 8 XCDs. Remap so each XCD owns a CONTIGUOUS run of work-ids, and
    // make tblk the fastest work coordinate -> adjacent t-strips (which share
    // the 3-row halo) run on the same XCD ~concurrently -> halo reads hit
    // that XCD's L2 instead of HBM. grid=2048 is divisible by 8 -> bijective.
    const int nwg  = Bsz * TBLK * DBLK;           // 2048
    const int cpx  = nwg / NXCD;                  // 256 work items per XCD
    const int wid  = (blockIdx.x % NXCD) * cpx + blockIdx.x / NXCD;

    const int tblk = wid % TBLK;                  // fastest: contiguous t-strips
    const int rest = wid / TBLK;
    const int dblk = rest % DBLK;
    const int b    = rest / DBLK;

    const int d4 = dblk * THREADS + threadIdx.x;  // this thread's float4 column
    const int t0 = tblk * TT;

    const f4* x4 = reinterpret_cast<const f4*>(x) + (size_t)b * T * D4 + d4;
    f4*       o4 = reinterpret_cast<f4*>(out)     + (size_t)b * T * D4 + d4;

    // ---- Phase 1: issue ALL strip loads back-to-back (19 independent
    // global_load_dwordx4 in flight per wave -> high MLP). Static indexing
    // only (full unroll) so xr[] stays in registers.
    f4 xr[TT + 3];
    const int tm3 = t0 - 3;
    if (t0 == 0) {
        const f4 z = {0.f, 0.f, 0.f, 0.f};
        xr[0] = z; xr[1] = z; xr[2] = z;
#pragma unroll
        for (int i = 3; i < TT + 3; ++i)
            xr[i] = x4[(size_t)(tm3 + i) * D4];
    } else {
#pragma unroll
        for (int i = 0; i < TT + 3; ++i)
            xr[i] = x4[(size_t)(tm3 + i) * D4];
    }

    // Per-channel weights: w[d][k], k fastest -> one f4 per channel.
    const f4* w4 = reinterpret_cast<const f4*>(w);
    const f4 wr0 = w4[d4 * 4 + 0];
    const f4 wr1 = w4[d4 * 4 + 1];
    const f4 wr2 = w4[d4 * 4 + 2];
    const f4 wr3 = w4[d4 * 4 + 3];
    const f4 bb  = reinterpret_cast<const f4*>(bias)[d4];

    // Transpose to tap-major: wk{k} holds tap-k weights for the 4 channels.
    const f4 wk0 = {wr0.x, wr1.x, wr2.x, wr3.x};
    const f4 wk1 = {wr0.y, wr1.y, wr2.y, wr3.y};
    const f4 wk2 = {wr0.z, wr1.z, wr2.z, wr3.z};
    const f4 wk3 = {wr0.w, wr1.w, wr2.w, wr3.w};

    // ---- Phase 2: compute + non-temporal store (output is never re-read;
    // don't displace x from L2/L3).
#pragma unroll
    for (int i = 0; i < TT; ++i) {
        const f4 a = xr[i];       // x[t-3]
        const f4 c = xr[i + 1];   // x[t-2]
        const f4 d = xr[i + 2];   // x[t-1]
        const f4 e = xr[i + 3];   // x[t]

        f4 y;
        y.x = fmaf(wk0.x, a.x, fmaf(wk1.x, c.x, fmaf(wk2.x, d.x, fmaf(wk3.x, e.x, bb.x))));
        y.y = fmaf(wk0.y, a.y, fmaf(wk1.y, c.y, fmaf(wk2.y, d.y, fmaf(wk3.y, e.y, bb.y))));
        y.z = fmaf(wk0.z, a.z, fmaf(wk1.z, c.z, fmaf(wk2.z, d.z, fmaf(wk3.z, e.z, bb.z))));
        y.w = fmaf(wk0.w, a.w, fmaf(wk1.w, c.w, fmaf(wk2.w, d.w, fmaf(wk3.w, e.w, bb.w))));

        __builtin_nontemporal_store(silu4(y), &o4[(size_t)(t0 + i) * D4]);
    }
}

extern "C" void kernel_launch(void* const* d_in, const int* in_sizes, int n_in,
                              void* d_out, int out_size, void* d_ws, size_t ws_size,
                              hipStream_t stream) {
    const float* x    = (const float*)d_in[0];
    const float* w    = (const float*)d_in[1];
    const float* bias = (const float*)d_in[2];
    float*       out  = (float*)d_out;

    const int grid = Bsz * TBLK * DBLK;  // 4 * 256 * 2 = 2048 blocks
    shortconv_silu_kernel<<<grid, THREADS, 0, stream>>>(x, w, bias, out);
}